// Round 1
// baseline (260.487 us; speedup 1.0000x reference)
//
#include <hip/hip_runtime.h>
#include <hip/hip_bf16.h>
#include <cstdint>
#include <cstddef>

// ---------------- problem constants ----------------
constexpr int Bn   = 8;
constexpr int Hn   = 64;
constexpr int Wn   = 64;
constexpr int Cn   = 256;
constexpr int OUTC = 1024;
constexpr int HPAD = 66;   // 64 + 2 halo
constexpr int WPAD = 66;
#define EPS 1e-5f

typedef __attribute__((ext_vector_type(4))) float f32x4;
typedef __bf16 bf16x8 __attribute__((ext_vector_type(8)));

// ---------------- helpers ----------------
__device__ __forceinline__ void gload_lds16(const void* g, void* l) {
    __builtin_amdgcn_global_load_lds(
        (__attribute__((address_space(1))) void*)g,
        (__attribute__((address_space(3))) void*)l,
        16, 0, 0);
}

// ---------------- K0: conv_w [3][3][256][1024] f32 -> wT [9][1024][256] bf16 ----------------
__global__ __launch_bounds__(256) void k0_transpose_w(const float* __restrict__ conv_w,
                                                      __hip_bfloat16* __restrict__ wT) {
    __shared__ float tile[64][65];
    const int tap = blockIdx.x;        // 0..8
    const int ct  = blockIdx.y;        // c-tile 0..3  (64 ch)
    const int ot  = blockIdx.z;        // o-tile 0..15 (64 out)
    const int t   = threadIdx.x;
    const int lo  = t & 63;
    const int cq  = t >> 6;            // 0..3

#pragma unroll
    for (int k = 0; k < 16; ++k) {
        int ci = k * 4 + cq;
        tile[lo][ci] = conv_w[((size_t)(tap * Cn + ct * 64 + ci)) * OUTC + ot * 64 + lo];
    }
    __syncthreads();
#pragma unroll
    for (int k = 0; k < 16; ++k) {
        int oo = k * 4 + cq;
        wT[((size_t)(tap * OUTC + ot * 64 + oo)) * Cn + ct * 64 + lo] =
            __float2bfloat16(tile[oo][lo]);
    }
}

// ---------------- K1: per-(b,h) partial sums over w ----------------
__global__ __launch_bounds__(256) void k1_stats_partial(const float* __restrict__ x,
                                                        float* __restrict__ ps,
                                                        float* __restrict__ pq) {
    const int bh = blockIdx.x;          // b*64 + h
    const int c  = threadIdx.x;
    const float* row = x + (size_t)bh * Wn * Cn + c;
    float s = 0.f, q = 0.f;
#pragma unroll 8
    for (int w = 0; w < Wn; ++w) {
        float v = row[(size_t)w * Cn];
        s += v; q += v * v;
    }
    ps[bh * Cn + c] = s;
    pq[bh * Cn + c] = q;
}

// ---------------- K2: reduce over h, produce scale/shift ----------------
__global__ __launch_bounds__(256) void k2_stats_final(const float* __restrict__ ps,
                                                      const float* __restrict__ pq,
                                                      float* __restrict__ scale,
                                                      float* __restrict__ shift) {
    const int b = blockIdx.x;
    const int c = threadIdx.x;
    float s = 0.f, q = 0.f;
    for (int h = 0; h < Hn; ++h) {
        s += ps[(b * Hn + h) * Cn + c];
        q += pq[(b * Hn + h) * Cn + c];
    }
    const float inv = 1.f / (float)(Hn * Wn);
    float mean = s * inv;
    float var  = fmaxf(q * inv - mean * mean, 0.f);
    float sc   = 1.f / (sqrtf(var) + EPS);
    scale[b * Cn + c] = sc;
    shift[b * Cn + c] = -mean * sc;
}

// ---------------- K3: norm + depthwise 3x3 + pointwise + bias -> t_pad bf16 ----------------
__global__ __launch_bounds__(256) void k3_dwconv(const float* __restrict__ x,
                                                 const float* __restrict__ w_sp,
                                                 const float* __restrict__ w_pw,
                                                 const float* __restrict__ bias,
                                                 const float* __restrict__ scale,
                                                 const float* __restrict__ shift,
                                                 __hip_bfloat16* __restrict__ tpad) {
    const int bh = blockIdx.x;
    const int b  = bh / HPAD;
    const int hp = bh - b * HPAD;       // 0..65
    const int c  = threadIdx.x;
    __hip_bfloat16* orow = tpad + ((size_t)(b * HPAD + hp)) * WPAD * Cn + c;
    const __hip_bfloat16 z = __float2bfloat16(0.f);

    if (hp == 0 || hp == HPAD - 1) {
        for (int wp = 0; wp < WPAD; ++wp) orow[(size_t)wp * Cn] = z;
        return;
    }
    const int h = hp - 1;
    const float sc = scale[b * Cn + c];
    const float sh = shift[b * Cn + c];
    float w9[9];
#pragma unroll
    for (int k = 0; k < 9; ++k) w9[k] = w_sp[(b * 9 + k) * Cn + c];
    const float pw = w_pw[b * Cn + c];
    const float bv = bias[b * Cn + c];
    const float* xb = x + (size_t)b * Hn * Wn * Cn + c;

    bool rv[3];
#pragma unroll
    for (int r = 0; r < 3; ++r) { int rr = h - 1 + r; rv[r] = (rr >= 0 && rr < Hn); }

    float win[3][3];
#pragma unroll
    for (int r = 0; r < 3; ++r) {
        win[r][0] = 0.f;
        win[r][1] = rv[r] ? (xb[((size_t)(h - 1 + r) * Wn) * Cn] * sc + sh) : 0.f;
    }
    orow[0] = z;
    orow[(size_t)(WPAD - 1) * Cn] = z;

    for (int w = 0; w < Wn; ++w) {
#pragma unroll
        for (int r = 0; r < 3; ++r)
            win[r][2] = (rv[r] && (w + 1) < Wn)
                        ? (xb[((size_t)(h - 1 + r) * Wn + (w + 1)) * Cn] * sc + sh) : 0.f;
        float y = 0.f;
#pragma unroll
        for (int r = 0; r < 3; ++r)
#pragma unroll
            for (int qq = 0; qq < 3; ++qq)
                y += win[r][qq] * w9[r * 3 + qq];
        orow[(size_t)(w + 1) * Cn] = __float2bfloat16(y * pw + bv);
#pragma unroll
        for (int r = 0; r < 3; ++r) { win[r][0] = win[r][1]; win[r][1] = win[r][2]; }
    }
}

// ---------------- K4: implicit-GEMM 3x3 conv, 256 -> 1024, bf16 MFMA ----------------
// grid: (8 n-tiles, 256 m-tiles) ; block 256 threads = 4 waves (2x2), tile 128x128, BK=64
__global__ __launch_bounds__(256) void k4_gemm(const __hip_bfloat16* __restrict__ tpad,
                                               const __hip_bfloat16* __restrict__ wT,
                                               const float* __restrict__ conv_b,
                                               float* __restrict__ out) {
    __shared__ __align__(16) char smem[32768];   // As 16KB | Bs 16KB

    const int tid  = threadIdx.x;
    const int lane = tid & 63;
    const int wv   = tid >> 6;
    const int wm   = wv >> 1, wn = wv & 1;
    const int g    = lane >> 4, l15 = lane & 15;

    const int obase   = blockIdx.x * 128;
    const int by      = blockIdx.y;
    const int b       = by >> 5;
    const int pixbase = (by & 31) * 128;

    // staging source offsets (elements). LDS 16B-unit u = i*256 + tid.
    // row = u>>3, slot = u&7, source k-slot sg = slot ^ (row&7)  (XOR involution, rule #21)
    int a_off[4], b_off[4];
#pragma unroll
    for (int i = 0; i < 4; ++i) {
        int u   = i * 256 + tid;
        int row = u >> 3;
        int sg  = (u & 7) ^ (row & 7);
        int p   = pixbase + row;
        int h   = p >> 6, w = p & 63;
        a_off[i] = ((b * HPAD + h) * WPAD + w) * Cn + sg * 8;
        b_off[i] = (obase + row) * Cn + sg * 8;
    }
    const int ldsu = (tid >> 6) << 6;   // wave-uniform base lane-unit within 256

    f32x4 acc[4][4] = {};

#pragma unroll 1
    for (int tap = 0; tap < 9; ++tap) {
        const int kh = tap / 3, kw = tap - kh * 3;
        const __hip_bfloat16* aSrc = tpad + (kh * WPAD + kw) * Cn;
        const __hip_bfloat16* bSrc = wT + (size_t)tap * (OUTC * Cn);
#pragma unroll 1
        for (int ks = 0; ks < 4; ++ks) {
            const int kbase = ks * 64;
#pragma unroll
            for (int i = 0; i < 4; ++i) {
                gload_lds16(aSrc + a_off[i] + kbase, smem + (size_t)(i * 256 + ldsu) * 16);
                gload_lds16(bSrc + b_off[i] + kbase, smem + 16384 + (size_t)(i * 256 + ldsu) * 16);
            }
            __syncthreads();   // drains vmcnt -> LDS tiles ready
#pragma unroll
            for (int half = 0; half < 2; ++half) {
                bf16x8 af[4], bfrag[4];
                const int colb = g * 16 + half * 64;
#pragma unroll
                for (int m = 0; m < 4; ++m) {
                    int row = wm * 64 + m * 16 + l15;
                    af[m] = *(const bf16x8*)(smem + row * 128 + (colb ^ ((row & 7) << 4)));
                }
#pragma unroll
                for (int n = 0; n < 4; ++n) {
                    int row = wn * 64 + n * 16 + l15;
                    bfrag[n] = *(const bf16x8*)(smem + 16384 + row * 128 + (colb ^ ((row & 7) << 4)));
                }
#pragma unroll
                for (int m = 0; m < 4; ++m)
#pragma unroll
                    for (int n = 0; n < 4; ++n)
                        acc[m][n] = __builtin_amdgcn_mfma_f32_16x16x32_bf16(
                            af[m], bfrag[n], acc[m][n], 0, 0, 0);
            }
            __syncthreads();   // all waves done reading before next overwrite
        }
    }

    // epilogue: C frag layout col = l&15, row = (l>>4)*4 + j  (m89-verified)
    float cb[4];
#pragma unroll
    for (int n = 0; n < 4; ++n) cb[n] = conv_b[obase + wn * 64 + n * 16 + l15];
#pragma unroll
    for (int m = 0; m < 4; ++m) {
#pragma unroll
        for (int j = 0; j < 4; ++j) {
            int r = pixbase + wm * 64 + m * 16 + g * 4 + j;
            float* orow = out + ((size_t)(b * 4096 + r)) * OUTC + obase + wn * 64 + l15;
#pragma unroll
            for (int n = 0; n < 4; ++n)
                orow[n * 16] = acc[m][n][j] + cb[n];
        }
    }
}

// ---------------- launch ----------------
extern "C" void kernel_launch(void* const* d_in, const int* in_sizes, int n_in,
                              void* d_out, int out_size, void* d_ws, size_t ws_size,
                              hipStream_t stream) {
    const float* x      = (const float*)d_in[0];
    const float* w_sp   = (const float*)d_in[1];
    const float* w_pw   = (const float*)d_in[2];
    const float* bias   = (const float*)d_in[3];
    const float* conv_w = (const float*)d_in[4];
    const float* conv_b = (const float*)d_in[5];
    float* out = (float*)d_out;

    char* ws = (char*)d_ws;
    // workspace layout (bytes):
    //   wT    : 9*1024*256*2            = 4,718,592
    //   ps    : 8*64*256*4              =   524,288
    //   pq    : 8*64*256*4              =   524,288
    //   scale : 8*256*4                 =     8,192
    //   shift : 8*256*4                 =     8,192
    //   tpad  : 8*66*66*256*2           = 17,842,176   -> total 23,625,728
    __hip_bfloat16* wT    = (__hip_bfloat16*)(ws);
    float*          ps    = (float*)(ws + 4718592);
    float*          pq    = (float*)(ws + 4718592 + 524288);
    float*          scale = (float*)(ws + 5767168);
    float*          shift = (float*)(ws + 5775360);
    __hip_bfloat16* tpad  = (__hip_bfloat16*)(ws + 5783552);

    k0_transpose_w<<<dim3(9, 4, 16), 256, 0, stream>>>(conv_w, wT);
    k1_stats_partial<<<Bn * Hn, 256, 0, stream>>>(x, ps, pq);
    k2_stats_final<<<Bn, 256, 0, stream>>>(ps, pq, scale, shift);
    k3_dwconv<<<Bn * HPAD, 256, 0, stream>>>(x, w_sp, w_pw, bias, scale, shift, tpad);
    k4_gemm<<<dim3(8, 256), 256, 0, stream>>>(tpad, wT, conv_b, out);
}

// Round 2
// 210.409 us; speedup vs baseline: 1.2380x; 1.2380x over previous
//
#include <hip/hip_runtime.h>
#include <hip/hip_bf16.h>
#include <cstdint>
#include <cstddef>

// ---------------- problem constants ----------------
constexpr int Bn   = 8;
constexpr int Hn   = 64;
constexpr int Wn   = 64;
constexpr int Cn   = 256;
constexpr int OUTC = 1024;
constexpr int HPAD = 66;   // 64 + 2 halo
constexpr int WPAD = 66;
#define EPS 1e-5f

typedef __attribute__((ext_vector_type(4))) float f32x4;
typedef __bf16 bf16x8 __attribute__((ext_vector_type(8)));

// ---------------- helpers ----------------
__device__ __forceinline__ void gload_lds16(const void* g, void* l) {
    __builtin_amdgcn_global_load_lds(
        (__attribute__((address_space(1))) void*)g,
        (__attribute__((address_space(3))) void*)l,
        16, 0, 0);
}

// ---------------- K0: conv_w [3][3][256][1024] f32 -> wT [9][1024][256] bf16 ----------------
__global__ __launch_bounds__(256) void k0_transpose_w(const float* __restrict__ conv_w,
                                                      __hip_bfloat16* __restrict__ wT) {
    __shared__ float tile[64][65];
    const int tap = blockIdx.x;        // 0..8
    const int ct  = blockIdx.y;        // c-tile 0..3  (64 ch)
    const int ot  = blockIdx.z;        // o-tile 0..15 (64 out)
    const int t   = threadIdx.x;
    const int lo  = t & 63;
    const int cq  = t >> 6;            // 0..3

#pragma unroll
    for (int k = 0; k < 16; ++k) {
        int ci = k * 4 + cq;
        tile[lo][ci] = conv_w[((size_t)(tap * Cn + ct * 64 + ci)) * OUTC + ot * 64 + lo];
    }
    __syncthreads();
#pragma unroll
    for (int k = 0; k < 16; ++k) {
        int oo = k * 4 + cq;
        wT[((size_t)(tap * OUTC + ot * 64 + oo)) * Cn + ct * 64 + lo] =
            __float2bfloat16(tile[oo][lo]);
    }
}

// ---------------- K1: per-(b,h) sums over w (1024 thr: 4 w-slices x 256 ch) ----------------
__global__ __launch_bounds__(1024) void k1_stats_partial(const float* __restrict__ x,
                                                         float* __restrict__ ps,
                                                         float* __restrict__ pq) {
    __shared__ float sb[2][4][256];
    const int bh = blockIdx.x;          // b*64 + h
    const int tid = threadIdx.x;
    const int c = tid & 255;
    const int s = tid >> 8;             // 0..3
    const float* row = x + (size_t)bh * Wn * Cn + (size_t)s * 16 * Cn + c;
    float sm = 0.f, q = 0.f;
#pragma unroll
    for (int w = 0; w < 16; ++w) {
        float v = row[(size_t)w * Cn];
        sm += v; q += v * v;
    }
    sb[0][s][c] = sm; sb[1][s][c] = q;
    __syncthreads();
    if (s == 0) {
        float S = 0.f, Q = 0.f;
#pragma unroll
        for (int k = 0; k < 4; ++k) { S += sb[0][k][c]; Q += sb[1][k][c]; }
        ps[bh * Cn + c] = S;
        pq[bh * Cn + c] = Q;
    }
}

// ---------------- K2: reduce over h, produce scale/shift (1024 thr) ----------------
__global__ __launch_bounds__(1024) void k2_stats_final(const float* __restrict__ ps,
                                                       const float* __restrict__ pq,
                                                       float* __restrict__ scale,
                                                       float* __restrict__ shift) {
    __shared__ float sb[2][4][256];
    const int b = blockIdx.x;
    const int tid = threadIdx.x;
    const int c = tid & 255;
    const int qd = tid >> 8;            // 0..3, each sums 16 h
    float S = 0.f, Q = 0.f;
#pragma unroll 4
    for (int i = 0; i < 16; ++i) {
        int h = qd * 16 + i;
        S += ps[(b * Hn + h) * Cn + c];
        Q += pq[(b * Hn + h) * Cn + c];
    }
    sb[0][qd][c] = S; sb[1][qd][c] = Q;
    __syncthreads();
    if (qd == 0) {
        float s2 = 0.f, q2 = 0.f;
#pragma unroll
        for (int k = 0; k < 4; ++k) { s2 += sb[0][k][c]; q2 += sb[1][k][c]; }
        const float inv = 1.f / (float)(Hn * Wn);
        float mean = s2 * inv;
        float var  = fmaxf(q2 * inv - mean * mean, 0.f);
        float sc   = 1.f / (sqrtf(var) + EPS);
        scale[b * Cn + c] = sc;
        shift[b * Cn + c] = -mean * sc;
    }
}

// ---------------- K3: norm + depthwise 3x3 + pointwise + bias -> t_pad bf16 ----------------
// grid: B*HPAD*4 (4 w-quads of 16 output cols each)
__global__ __launch_bounds__(256) void k3_dwconv(const float* __restrict__ x,
                                                 const float* __restrict__ w_sp,
                                                 const float* __restrict__ w_pw,
                                                 const float* __restrict__ bias,
                                                 const float* __restrict__ scale,
                                                 const float* __restrict__ shift,
                                                 __hip_bfloat16* __restrict__ tpad) {
    const int bq = blockIdx.x;
    const int wq = bq & 3;
    const int bh = bq >> 2;
    const int b  = bh / HPAD;
    const int hp = bh - b * HPAD;       // 0..65
    const int c  = threadIdx.x;
    __hip_bfloat16* orow = tpad + ((size_t)(b * HPAD + hp)) * WPAD * Cn + c;
    const __hip_bfloat16 z = __float2bfloat16(0.f);

    if (hp == 0 || hp == HPAD - 1) {
        int wlo = wq * 17, whi = wlo + 17 < WPAD ? wlo + 17 : WPAD;
        for (int wp = wlo; wp < whi; ++wp) orow[(size_t)wp * Cn] = z;
        return;
    }
    const int h = hp - 1;
    const float sc = scale[b * Cn + c];
    const float sh = shift[b * Cn + c];
    float w9[9];
#pragma unroll
    for (int k = 0; k < 9; ++k) w9[k] = w_sp[(b * 9 + k) * Cn + c];
    const float pw = w_pw[b * Cn + c];
    const float bv = bias[b * Cn + c];
    const float* xb = x + (size_t)b * Hn * Wn * Cn + c;

    bool rv[3];
#pragma unroll
    for (int r = 0; r < 3; ++r) { int rr = h - 1 + r; rv[r] = (rr >= 0 && rr < Hn); }

    if (wq == 0) orow[0] = z;
    if (wq == 3) orow[(size_t)(WPAD - 1) * Cn] = z;

    const int w0 = wq * 16;
    float win[3][3];
#pragma unroll
    for (int r = 0; r < 3; ++r) {
        win[r][0] = (rv[r] && w0 > 0)
                    ? (xb[((size_t)(h - 1 + r) * Wn + (w0 - 1)) * Cn] * sc + sh) : 0.f;
        win[r][1] = rv[r] ? (xb[((size_t)(h - 1 + r) * Wn + w0) * Cn] * sc + sh) : 0.f;
    }
    for (int i = 0; i < 16; ++i) {
        const int w = w0 + i;
#pragma unroll
        for (int r = 0; r < 3; ++r)
            win[r][2] = (rv[r] && (w + 1) < Wn)
                        ? (xb[((size_t)(h - 1 + r) * Wn + (w + 1)) * Cn] * sc + sh) : 0.f;
        float y = 0.f;
#pragma unroll
        for (int r = 0; r < 3; ++r)
#pragma unroll
            for (int qq = 0; qq < 3; ++qq)
                y += win[r][qq] * w9[r * 3 + qq];
        orow[(size_t)(w + 1) * Cn] = __float2bfloat16(y * pw + bv);
#pragma unroll
        for (int r = 0; r < 3; ++r) { win[r][0] = win[r][1]; win[r][1] = win[r][2]; }
    }
}

// ---------------- K4: implicit-GEMM 3x3 conv, 8-phase-style deep pipeline ----------------
// BM=256 (pixels), BN=128 (out ch), BK=64; 512 thr = 8 waves (2m x 4n), per-wave 128x32.
// LDS: 3 buffers x (A 32KB + B 16KB) = 144KB; stage 2 K-steps ahead; boundary vmcnt(6).
constexpr int KSTEPS = 36;              // 9 taps x (256/64)
constexpr int BUFSZ  = 49152;           // A 32768 + B 16384

__global__ __launch_bounds__(512, 2) void k4_gemm(const __hip_bfloat16* __restrict__ tpad,
                                                  const __hip_bfloat16* __restrict__ wT,
                                                  const float* __restrict__ conv_b,
                                                  float* __restrict__ out) {
    __shared__ __align__(16) char smem[3 * BUFSZ];

    const int tid  = threadIdx.x;
    const int lane = tid & 63;
    const int wv   = tid >> 6;          // 0..7
    const int wm   = wv >> 2;           // 0..1
    const int wn   = wv & 3;            // 0..3
    const int g    = lane >> 4, l15 = lane & 15;

    // XCD-chunked mapping: xcd k owns m-tiles [16k,16k+16) across all 8 n-tiles
    const int bid = blockIdx.x;         // 0..1023
    const int mt  = (bid & 7) * 16 + ((bid >> 3) & 15);   // 0..127
    const int nt  = bid >> 7;                             // 0..7
    const int pixbase = mt * 256;       // global pixel row (includes batch)
    const int b       = pixbase >> 12;
    const int hbase   = (pixbase & 4095) >> 6;
    const int obase   = nt * 128;

    // ---- staging source offsets (XOR-swizzled k-slot, rule #21) ----
    // A: unit u = hh*1024 + j*512 + tid ; row=u>>3, slot=u&7, sg=slot^(row&7)
    int a_base[4];
#pragma unroll
    for (int hh = 0; hh < 2; ++hh)
#pragma unroll
        for (int j = 0; j < 2; ++j) {
            int u    = hh * 1024 + j * 512 + tid;
            int grow = u >> 3;
            int sg   = (u & 7) ^ (grow & 7);
            int h    = hbase + (grow >> 6);
            int w    = grow & 63;
            a_base[hh * 2 + j] = ((b * HPAD + h) * WPAD + w) * Cn + sg * 8;
        }
    int b_base[2];
#pragma unroll
    for (int j = 0; j < 2; ++j) {
        int u    = j * 512 + tid;
        int grow = u >> 3;
        int sg   = (u & 7) ^ (grow & 7);
        b_base[j] = (obase + grow) * Cn + sg * 8;
    }

    auto stageA = [&](int step, int hh) {
        const int tap = step >> 2, ks = step & 3;
        const int kh = tap / 3, kw = tap - 3 * kh;
        const __hip_bfloat16* src = tpad + (kh * WPAD + kw) * Cn + ks * 64;
        char* base = smem + (step % 3) * BUFSZ;
        gload_lds16(src + a_base[hh * 2 + 0], base + (hh * 1024 + 0   + wv * 64) * 16);
        gload_lds16(src + a_base[hh * 2 + 1], base + (hh * 1024 + 512 + wv * 64) * 16);
    };
    auto stageB = [&](int step) {
        const int tap = step >> 2, ks = step & 3;
        const __hip_bfloat16* src = wT + (size_t)tap * (OUTC * Cn) + ks * 64;
        char* base = smem + (step % 3) * BUFSZ + 32768;
        gload_lds16(src + b_base[0], base + (0   + wv * 64) * 16);
        gload_lds16(src + b_base[1], base + (512 + wv * 64) * 16);
    };

    f32x4 acc[8][2] = {};

    // ---- prologue: stage K-steps 0,1 ----
    stageA(0, 0); stageA(0, 1); stageB(0);
    stageA(1, 0); stageA(1, 1); stageB(1);
    asm volatile("s_waitcnt vmcnt(6)" ::: "memory");
    __builtin_amdgcn_s_barrier();
    __builtin_amdgcn_sched_barrier(0);

#pragma unroll 1
    for (int t = 0; t < KSTEPS; ++t) {
        char* Ab = smem + (t % 3) * BUFSZ;
        char* Bb = Ab + 32768;
        const bool pf = (t + 2 < KSTEPS);

        bf16x8 bfr[2][2];   // n, kh — read in P0, reused in P1
        bf16x8 af[4][2];

        // ================= phase 0: rows m=0..3 =================
#pragma unroll
        for (int n = 0; n < 2; ++n)
#pragma unroll
            for (int kh = 0; kh < 2; ++kh) {
                int row = wn * 32 + n * 16 + l15;
                bfr[n][kh] = *(const bf16x8*)(Bb + row * 128 +
                                ((kh * 64 + g * 16) ^ ((row & 7) << 4)));
            }
#pragma unroll
        for (int m = 0; m < 4; ++m)
#pragma unroll
            for (int kh = 0; kh < 2; ++kh) {
                int row = wm * 128 + m * 16 + l15;
                af[m][kh] = *(const bf16x8*)(Ab + row * 128 +
                                ((kh * 64 + g * 16) ^ ((row & 7) << 4)));
            }
        if (pf) stageA(t + 2, 0);
        __builtin_amdgcn_s_barrier();
        __builtin_amdgcn_sched_barrier(0);
        __builtin_amdgcn_s_setprio(1);
#pragma unroll
        for (int m = 0; m < 4; ++m)
#pragma unroll
            for (int n = 0; n < 2; ++n)
#pragma unroll
                for (int kh = 0; kh < 2; ++kh)
                    acc[m][n] = __builtin_amdgcn_mfma_f32_16x16x32_bf16(
                        af[m][kh], bfr[n][kh], acc[m][n], 0, 0, 0);
        __builtin_amdgcn_s_setprio(0);
        __builtin_amdgcn_s_barrier();
        __builtin_amdgcn_sched_barrier(0);

        // ================= phase 1: rows m=4..7 =================
#pragma unroll
        for (int m = 0; m < 4; ++m)
#pragma unroll
            for (int kh = 0; kh < 2; ++kh) {
                int row = wm * 128 + (m + 4) * 16 + l15;
                af[m][kh] = *(const bf16x8*)(Ab + row * 128 +
                                ((kh * 64 + g * 16) ^ ((row & 7) << 4)));
            }
        if (pf) { stageA(t + 2, 1); stageB(t + 2); }
        __builtin_amdgcn_s_barrier();
        __builtin_amdgcn_sched_barrier(0);
        __builtin_amdgcn_s_setprio(1);
#pragma unroll
        for (int m = 0; m < 4; ++m)
#pragma unroll
            for (int n = 0; n < 2; ++n)
#pragma unroll
                for (int kh = 0; kh < 2; ++kh)
                    acc[m + 4][n] = __builtin_amdgcn_mfma_f32_16x16x32_bf16(
                        af[m][kh], bfr[n][kh], acc[m + 4][n], 0, 0, 0);
        __builtin_amdgcn_s_setprio(0);

        // ---- K-step boundary: counted wait, never 0 in steady state ----
        if (pf) { asm volatile("s_waitcnt vmcnt(6)" ::: "memory"); }
        else    { asm volatile("s_waitcnt vmcnt(0)" ::: "memory"); }
        __builtin_amdgcn_s_barrier();
        __builtin_amdgcn_sched_barrier(0);
    }

    // ---- epilogue: C frag col = l15 (out ch), row = g*4+j (pixel) ----
    float cb[2];
#pragma unroll
    for (int n = 0; n < 2; ++n) cb[n] = conv_b[obase + wn * 32 + n * 16 + l15];
#pragma unroll
    for (int m = 0; m < 8; ++m) {
#pragma unroll
        for (int j = 0; j < 4; ++j) {
            int r = pixbase + wm * 128 + m * 16 + g * 4 + j;
            float* orow = out + (size_t)r * OUTC + obase + wn * 32 + l15;
#pragma unroll
            for (int n = 0; n < 2; ++n)
                orow[n * 16] = acc[m][n][j] + cb[n];
        }
    }
}

// ---------------- launch ----------------
extern "C" void kernel_launch(void* const* d_in, const int* in_sizes, int n_in,
                              void* d_out, int out_size, void* d_ws, size_t ws_size,
                              hipStream_t stream) {
    const float* x      = (const float*)d_in[0];
    const float* w_sp   = (const float*)d_in[1];
    const float* w_pw   = (const float*)d_in[2];
    const float* bias   = (const float*)d_in[3];
    const float* conv_w = (const float*)d_in[4];
    const float* conv_b = (const float*)d_in[5];
    float* out = (float*)d_out;

    char* ws = (char*)d_ws;
    // workspace layout (bytes):
    //   wT    : 9*1024*256*2            = 4,718,592
    //   ps    : 8*64*256*4              =   524,288
    //   pq    : 8*64*256*4              =   524,288
    //   scale : 8*256*4                 =     8,192
    //   shift : 8*256*4                 =     8,192
    //   tpad  : 8*66*66*256*2           = 17,842,176   -> total 23,625,728
    __hip_bfloat16* wT    = (__hip_bfloat16*)(ws);
    float*          ps    = (float*)(ws + 4718592);
    float*          pq    = (float*)(ws + 4718592 + 524288);
    float*          scale = (float*)(ws + 5767168);
    float*          shift = (float*)(ws + 5775360);
    __hip_bfloat16* tpad  = (__hip_bfloat16*)(ws + 5783552);

    k0_transpose_w<<<dim3(9, 4, 16), 256, 0, stream>>>(conv_w, wT);
    k1_stats_partial<<<Bn * Hn, 1024, 0, stream>>>(x, ps, pq);
    k2_stats_final<<<Bn, 1024, 0, stream>>>(ps, pq, scale, shift);
    k3_dwconv<<<Bn * HPAD * 4, 256, 0, stream>>>(x, w_sp, w_pw, bias, scale, shift, tpad);
    k4_gemm<<<1024, 512, 0, stream>>>(tpad, wT, conv_b, out);
}

// Round 3
// 203.585 us; speedup vs baseline: 1.2795x; 1.0335x over previous
//
#include <hip/hip_runtime.h>
#include <hip/hip_bf16.h>
#include <cstdint>
#include <cstddef>

// ---------------- problem constants ----------------
constexpr int Bn   = 8;
constexpr int Hn   = 64;
constexpr int Wn   = 64;
constexpr int Cn   = 256;
constexpr int OUTC = 1024;
constexpr int HPAD = 66;   // 64 + 2 halo
constexpr int WPAD = 66;
#define EPS 1e-5f

typedef __attribute__((ext_vector_type(4))) float f32x4;
typedef __bf16 bf16x8 __attribute__((ext_vector_type(8)));

// ---------------- helpers ----------------
__device__ __forceinline__ void gload_lds16(const void* g, void* l) {
    __builtin_amdgcn_global_load_lds(
        (__attribute__((address_space(1))) void*)g,
        (__attribute__((address_space(3))) void*)l,
        16, 0, 0);
}

// ---------------- K0: conv_w [3][3][256][1024] f32 -> wT [9][1024][256] bf16 ----------------
__global__ __launch_bounds__(256) void k0_transpose_w(const float* __restrict__ conv_w,
                                                      __hip_bfloat16* __restrict__ wT) {
    __shared__ float tile[64][65];
    const int tap = blockIdx.x;        // 0..8
    const int ct  = blockIdx.y;        // c-tile 0..3  (64 ch)
    const int ot  = blockIdx.z;        // o-tile 0..15 (64 out)
    const int t   = threadIdx.x;
    const int lo  = t & 63;
    const int cq  = t >> 6;            // 0..3

#pragma unroll
    for (int k = 0; k < 16; ++k) {
        int ci = k * 4 + cq;
        tile[lo][ci] = conv_w[((size_t)(tap * Cn + ct * 64 + ci)) * OUTC + ot * 64 + lo];
    }
    __syncthreads();
#pragma unroll
    for (int k = 0; k < 16; ++k) {
        int oo = k * 4 + cq;
        wT[((size_t)(tap * OUTC + ot * 64 + oo)) * Cn + ct * 64 + lo] =
            __float2bfloat16(tile[oo][lo]);
    }
}

// ---------------- K1: per-(b,h) sums over w (1024 thr: 4 w-slices x 256 ch) ----------------
__global__ __launch_bounds__(1024) void k1_stats_partial(const float* __restrict__ x,
                                                         float* __restrict__ ps,
                                                         float* __restrict__ pq) {
    __shared__ float sb[2][4][256];
    const int bh = blockIdx.x;          // b*64 + h
    const int tid = threadIdx.x;
    const int c = tid & 255;
    const int s = tid >> 8;             // 0..3
    const float* row = x + (size_t)bh * Wn * Cn + (size_t)s * 16 * Cn + c;
    float sm = 0.f, q = 0.f;
#pragma unroll
    for (int w = 0; w < 16; ++w) {
        float v = row[(size_t)w * Cn];
        sm += v; q += v * v;
    }
    sb[0][s][c] = sm; sb[1][s][c] = q;
    __syncthreads();
    if (s == 0) {
        float S = 0.f, Q = 0.f;
#pragma unroll
        for (int k = 0; k < 4; ++k) { S += sb[0][k][c]; Q += sb[1][k][c]; }
        ps[bh * Cn + c] = S;
        pq[bh * Cn + c] = Q;
    }
}

// ---------------- K2: reduce over h, produce scale/shift (1024 thr) ----------------
__global__ __launch_bounds__(1024) void k2_stats_final(const float* __restrict__ ps,
                                                       const float* __restrict__ pq,
                                                       float* __restrict__ scale,
                                                       float* __restrict__ shift) {
    __shared__ float sb[2][4][256];
    const int b = blockIdx.x;
    const int tid = threadIdx.x;
    const int c = tid & 255;
    const int qd = tid >> 8;            // 0..3, each sums 16 h
    float S = 0.f, Q = 0.f;
#pragma unroll 4
    for (int i = 0; i < 16; ++i) {
        int h = qd * 16 + i;
        S += ps[(b * Hn + h) * Cn + c];
        Q += pq[(b * Hn + h) * Cn + c];
    }
    sb[0][qd][c] = S; sb[1][qd][c] = Q;
    __syncthreads();
    if (qd == 0) {
        float s2 = 0.f, q2 = 0.f;
#pragma unroll
        for (int k = 0; k < 4; ++k) { s2 += sb[0][k][c]; q2 += sb[1][k][c]; }
        const float inv = 1.f / (float)(Hn * Wn);
        float mean = s2 * inv;
        float var  = fmaxf(q2 * inv - mean * mean, 0.f);
        float sc   = 1.f / (sqrtf(var) + EPS);
        scale[b * Cn + c] = sc;
        shift[b * Cn + c] = -mean * sc;
    }
}

// ---------------- K3: norm + depthwise 3x3 + pointwise + bias -> t_pad bf16 ----------------
// grid: B*HPAD*4 (4 w-quads of 16 output cols each)
__global__ __launch_bounds__(256) void k3_dwconv(const float* __restrict__ x,
                                                 const float* __restrict__ w_sp,
                                                 const float* __restrict__ w_pw,
                                                 const float* __restrict__ bias,
                                                 const float* __restrict__ scale,
                                                 const float* __restrict__ shift,
                                                 __hip_bfloat16* __restrict__ tpad) {
    const int bq = blockIdx.x;
    const int wq = bq & 3;
    const int bh = bq >> 2;
    const int b  = bh / HPAD;
    const int hp = bh - b * HPAD;       // 0..65
    const int c  = threadIdx.x;
    __hip_bfloat16* orow = tpad + ((size_t)(b * HPAD + hp)) * WPAD * Cn + c;
    const __hip_bfloat16 z = __float2bfloat16(0.f);

    if (hp == 0 || hp == HPAD - 1) {
        int wlo = wq * 17, whi = wlo + 17 < WPAD ? wlo + 17 : WPAD;
        for (int wp = wlo; wp < whi; ++wp) orow[(size_t)wp * Cn] = z;
        return;
    }
    const int h = hp - 1;
    const float sc = scale[b * Cn + c];
    const float sh = shift[b * Cn + c];
    float w9[9];
#pragma unroll
    for (int k = 0; k < 9; ++k) w9[k] = w_sp[(b * 9 + k) * Cn + c];
    const float pw = w_pw[b * Cn + c];
    const float bv = bias[b * Cn + c];
    const float* xb = x + (size_t)b * Hn * Wn * Cn + c;

    bool rv[3];
#pragma unroll
    for (int r = 0; r < 3; ++r) { int rr = h - 1 + r; rv[r] = (rr >= 0 && rr < Hn); }

    if (wq == 0) orow[0] = z;
    if (wq == 3) orow[(size_t)(WPAD - 1) * Cn] = z;

    const int w0 = wq * 16;
    float win[3][3];
#pragma unroll
    for (int r = 0; r < 3; ++r) {
        win[r][0] = (rv[r] && w0 > 0)
                    ? (xb[((size_t)(h - 1 + r) * Wn + (w0 - 1)) * Cn] * sc + sh) : 0.f;
        win[r][1] = rv[r] ? (xb[((size_t)(h - 1 + r) * Wn + w0) * Cn] * sc + sh) : 0.f;
    }
    for (int i = 0; i < 16; ++i) {
        const int w = w0 + i;
#pragma unroll
        for (int r = 0; r < 3; ++r)
            win[r][2] = (rv[r] && (w + 1) < Wn)
                        ? (xb[((size_t)(h - 1 + r) * Wn + (w + 1)) * Cn] * sc + sh) : 0.f;
        float y = 0.f;
#pragma unroll
        for (int r = 0; r < 3; ++r)
#pragma unroll
            for (int qq = 0; qq < 3; ++qq)
                y += win[r][qq] * w9[r * 3 + qq];
        orow[(size_t)(w + 1) * Cn] = __float2bfloat16(y * pw + bv);
#pragma unroll
        for (int r = 0; r < 3; ++r) { win[r][0] = win[r][1]; win[r][1] = win[r][2]; }
    }
}

// ---------------- K4: implicit-GEMM 3x3 conv, 256x256 tile, BK=32, triple-buffer ----------------
// 512 thr = 8 waves (2m x 4n), per-wave 128x64 -> 32 MFMA / 12 ds_read_b128 per K-step.
// LDS rows padded to 80B (64B data + 16B pad): 2-way banks, gload-linear dest.
// Stage 2 K-steps ahead, 5 gloads/step, boundary vmcnt(5) (counted, never 0 mid-loop).
constexpr int KSTEPS = 72;              // 9 taps x (256/32)
constexpr int AREG   = 20480;           // 256 rows x 80B
constexpr int BUFSZ  = 40960;           // A 20KB + B 20KB

__global__ __launch_bounds__(512, 2) void k4_gemm(const __hip_bfloat16* __restrict__ tpad,
                                                  const __hip_bfloat16* __restrict__ wT,
                                                  const float* __restrict__ conv_b,
                                                  float* __restrict__ out) {
    __shared__ __align__(16) char smem[3 * BUFSZ];   // 120 KB

    const int tid  = threadIdx.x;
    const int lane = tid & 63;
    const int wv   = tid >> 6;          // 0..7
    const int wm   = wv >> 2;           // 0..1
    const int wn   = wv & 3;            // 0..3
    const int g    = lane >> 4, l15 = lane & 15;

    // XCD-chunked mapping (bijective: 8 x 16 x 4 = 512)
    const int bid = blockIdx.x;
    const int mt  = (bid & 7) * 16 + ((bid >> 3) & 15);   // 0..127
    const int nt  = bid >> 7;                             // 0..3
    const int pixbase = mt * 256;
    const int b       = mt >> 4;
    const int hbase   = (mt & 15) * 4;
    const int obase   = nt * 256;

    // ---- per-thread staging source offsets for 5 units u = j*512 + tid ----
    // physical LDS byte (linear for gload) = u*16 ; A units u<1280 (row=u/5,slot=u%5),
    // B units v=u-1280 (row=v/5, slot=v%5); slot==4 is pad (dup slot-0 source, never read).
    int off5[5];
#pragma unroll
    for (int j = 0; j < 5; ++j) {
        int u = j * 512 + tid;
        if (u < 1280) {
            int row = u / 5, rs = u - row * 5;
            int ls  = (rs == 4) ? 0 : rs;
            int h   = hbase + (row >> 6);
            int w   = row & 63;
            off5[j] = ((b * HPAD + h) * WPAD + w) * Cn + ls * 8;
        } else {
            int v = u - 1280;
            int row = v / 5, rs = v - row * 5;
            int ls  = (rs == 4) ? 0 : rs;
            off5[j] = (obase + row) * Cn + ls * 8;
        }
    }

    auto stageJ = [&](int s, int j0, int j1) {
        const int tap = s >> 3, ks = s & 7;
        const int kh  = (tap * 11) >> 5;
        const int kw  = tap - kh * 3;
        const __hip_bfloat16* aS = tpad + ((kh * WPAD + kw) * Cn + ks * 32);
        const __hip_bfloat16* bS = wT + (size_t)tap * (OUTC * Cn) + ks * 32;
        char* buf = smem + (s % 3) * BUFSZ;
#pragma unroll
        for (int j = 0; j < 5; ++j) {
            if (j < j0 || j > j1) continue;
            const __hip_bfloat16* src;
            if (j <= 1)      src = aS + off5[j];
            else if (j == 2) src = (tid < 256 ? aS : bS) + off5[j];
            else             src = bS + off5[j];
            gload_lds16(src, buf + (size_t)(j * 512 + wv * 64) * 16);
        }
    };

    f32x4 acc[8][4] = {};

    // ---- prologue: stage K-steps 0,1 (10 loads) ; wait oldest 5 ----
    stageJ(0, 0, 4);
    stageJ(1, 0, 4);
    asm volatile("s_waitcnt vmcnt(5)" ::: "memory");
    __builtin_amdgcn_s_barrier();
    __builtin_amdgcn_sched_barrier(0);

#pragma unroll 1
    for (int t = 0; t < KSTEPS; ++t) {
        char* Ab = smem + (t % 3) * BUFSZ;
        char* Bb = Ab + AREG;
        const bool pf = (t + 2 < KSTEPS);

        bf16x8 bfr[4];
        bf16x8 af[4];

        // ============ phase 0: B frags + A rows m=0..3 ; stage j=0..2 ============
#pragma unroll
        for (int n = 0; n < 4; ++n) {
            int row = wn * 64 + n * 16 + l15;
            bfr[n] = *(const bf16x8*)(Bb + row * 80 + g * 16);
        }
#pragma unroll
        for (int m = 0; m < 4; ++m) {
            int row = wm * 128 + m * 16 + l15;
            af[m] = *(const bf16x8*)(Ab + row * 80 + g * 16);
        }
        if (pf) stageJ(t + 2, 0, 2);
        __builtin_amdgcn_s_barrier();
        __builtin_amdgcn_sched_barrier(0);
        __builtin_amdgcn_s_setprio(1);
#pragma unroll
        for (int m = 0; m < 4; ++m)
#pragma unroll
            for (int n = 0; n < 4; ++n)
                acc[m][n] = __builtin_amdgcn_mfma_f32_16x16x32_bf16(
                    af[m], bfr[n], acc[m][n], 0, 0, 0);
        __builtin_amdgcn_s_setprio(0);
        __builtin_amdgcn_s_barrier();
        __builtin_amdgcn_sched_barrier(0);

        // ============ phase 1: A rows m=4..7 ; stage j=3..4 ============
#pragma unroll
        for (int m = 0; m < 4; ++m) {
            int row = wm * 128 + (m + 4) * 16 + l15;
            af[m] = *(const bf16x8*)(Ab + row * 80 + g * 16);
        }
        if (pf) stageJ(t + 2, 3, 4);
        __builtin_amdgcn_s_barrier();
        __builtin_amdgcn_sched_barrier(0);
        __builtin_amdgcn_s_setprio(1);
#pragma unroll
        for (int m = 0; m < 4; ++m)
#pragma unroll
            for (int n = 0; n < 4; ++n)
                acc[m + 4][n] = __builtin_amdgcn_mfma_f32_16x16x32_bf16(
                    af[m], bfr[n], acc[m + 4][n], 0, 0, 0);
        __builtin_amdgcn_s_setprio(0);

        // ---- K-step boundary: counted wait (t+1's 5 loads done, t+2's 5 in flight) ----
        if (pf)                      { asm volatile("s_waitcnt vmcnt(5)" ::: "memory"); }
        else if (t + 1 < KSTEPS)     { asm volatile("s_waitcnt vmcnt(0)" ::: "memory"); }
        __builtin_amdgcn_s_barrier();
        __builtin_amdgcn_sched_barrier(0);
    }

    // ---- epilogue: C frag col = l15, row = g*4+j ----
    float cb[4];
#pragma unroll
    for (int n = 0; n < 4; ++n) cb[n] = conv_b[obase + wn * 64 + n * 16 + l15];
#pragma unroll
    for (int m = 0; m < 8; ++m) {
#pragma unroll
        for (int j = 0; j < 4; ++j) {
            int r = pixbase + wm * 128 + m * 16 + g * 4 + j;
            float* orow = out + (size_t)r * OUTC + obase + wn * 64 + l15;
#pragma unroll
            for (int n = 0; n < 4; ++n)
                orow[n * 16] = acc[m][n][j] + cb[n];
        }
    }
}

// ---------------- launch ----------------
extern "C" void kernel_launch(void* const* d_in, const int* in_sizes, int n_in,
                              void* d_out, int out_size, void* d_ws, size_t ws_size,
                              hipStream_t stream) {
    const float* x      = (const float*)d_in[0];
    const float* w_sp   = (const float*)d_in[1];
    const float* w_pw   = (const float*)d_in[2];
    const float* bias   = (const float*)d_in[3];
    const float* conv_w = (const float*)d_in[4];
    const float* conv_b = (const float*)d_in[5];
    float* out = (float*)d_out;

    char* ws = (char*)d_ws;
    __hip_bfloat16* wT    = (__hip_bfloat16*)(ws);
    float*          ps    = (float*)(ws + 4718592);
    float*          pq    = (float*)(ws + 4718592 + 524288);
    float*          scale = (float*)(ws + 5767168);
    float*          shift = (float*)(ws + 5775360);
    __hip_bfloat16* tpad  = (__hip_bfloat16*)(ws + 5783552);

    k0_transpose_w<<<dim3(9, 4, 16), 256, 0, stream>>>(conv_w, wT);
    k1_stats_partial<<<Bn * Hn, 1024, 0, stream>>>(x, ps, pq);
    k2_stats_final<<<Bn, 1024, 0, stream>>>(ps, pq, scale, shift);
    k3_dwconv<<<Bn * HPAD * 4, 256, 0, stream>>>(x, w_sp, w_pw, bias, scale, shift, tpad);
    k4_gemm<<<512, 512, 0, stream>>>(tpad, wT, conv_b, out);
}

// Round 4
// 176.522 us; speedup vs baseline: 1.4757x; 1.1533x over previous
//
#include <hip/hip_runtime.h>
#include <hip/hip_bf16.h>
#include <cstdint>
#include <cstddef>

// ---------------- problem constants ----------------
constexpr int Bn   = 8;
constexpr int Hn   = 64;
constexpr int Wn   = 64;
constexpr int Cn   = 256;
constexpr int OUTC = 1024;
constexpr int HPAD = 66;   // 64 + 2 halo
constexpr int WPAD = 66;
#define EPS 1e-5f

typedef __attribute__((ext_vector_type(4))) float f32x4;
typedef __bf16 bf16x8 __attribute__((ext_vector_type(8)));

// ---------------- helpers ----------------
__device__ __forceinline__ void gload_lds16(const void* g, void* l) {
    __builtin_amdgcn_global_load_lds(
        (__attribute__((address_space(1))) void*)g,
        (__attribute__((address_space(3))) void*)l,
        16, 0, 0);
}

// ---------------- K0: conv_w [3][3][256][1024] f32 -> wT [9][1024][256] bf16 ----------------
__global__ __launch_bounds__(256) void k0_transpose_w(const float* __restrict__ conv_w,
                                                      __hip_bfloat16* __restrict__ wT) {
    __shared__ float tile[64][65];
    const int tap = blockIdx.x;        // 0..8
    const int ct  = blockIdx.y;        // c-tile 0..3  (64 ch)
    const int ot  = blockIdx.z;        // o-tile 0..15 (64 out)
    const int t   = threadIdx.x;
    const int lo  = t & 63;
    const int cq  = t >> 6;            // 0..3

#pragma unroll
    for (int k = 0; k < 16; ++k) {
        int ci = k * 4 + cq;
        tile[lo][ci] = conv_w[((size_t)(tap * Cn + ct * 64 + ci)) * OUTC + ot * 64 + lo];
    }
    __syncthreads();
#pragma unroll
    for (int k = 0; k < 16; ++k) {
        int oo = k * 4 + cq;
        wT[((size_t)(tap * OUTC + ot * 64 + oo)) * Cn + ct * 64 + lo] =
            __float2bfloat16(tile[oo][lo]);
    }
}

// ---------------- K1: per-(b,h) sums over w (1024 thr: 4 w-slices x 256 ch) ----------------
__global__ __launch_bounds__(1024) void k1_stats_partial(const float* __restrict__ x,
                                                         float* __restrict__ ps,
                                                         float* __restrict__ pq) {
    __shared__ float sb[2][4][256];
    const int bh = blockIdx.x;          // b*64 + h
    const int tid = threadIdx.x;
    const int c = tid & 255;
    const int s = tid >> 8;             // 0..3
    const float* row = x + (size_t)bh * Wn * Cn + (size_t)s * 16 * Cn + c;
    float sm = 0.f, q = 0.f;
#pragma unroll
    for (int w = 0; w < 16; ++w) {
        float v = row[(size_t)w * Cn];
        sm += v; q += v * v;
    }
    sb[0][s][c] = sm; sb[1][s][c] = q;
    __syncthreads();
    if (s == 0) {
        float S = 0.f, Q = 0.f;
#pragma unroll
        for (int k = 0; k < 4; ++k) { S += sb[0][k][c]; Q += sb[1][k][c]; }
        ps[bh * Cn + c] = S;
        pq[bh * Cn + c] = Q;
    }
}

// ---------------- K2: reduce over h, produce scale/shift (1024 thr) ----------------
__global__ __launch_bounds__(1024) void k2_stats_final(const float* __restrict__ ps,
                                                       const float* __restrict__ pq,
                                                       float* __restrict__ scale,
                                                       float* __restrict__ shift) {
    __shared__ float sb[2][4][256];
    const int b = blockIdx.x;
    const int tid = threadIdx.x;
    const int c = tid & 255;
    const int qd = tid >> 8;            // 0..3, each sums 16 h
    float S = 0.f, Q = 0.f;
#pragma unroll 4
    for (int i = 0; i < 16; ++i) {
        int h = qd * 16 + i;
        S += ps[(b * Hn + h) * Cn + c];
        Q += pq[(b * Hn + h) * Cn + c];
    }
    sb[0][qd][c] = S; sb[1][qd][c] = Q;
    __syncthreads();
    if (qd == 0) {
        float s2 = 0.f, q2 = 0.f;
#pragma unroll
        for (int k = 0; k < 4; ++k) { s2 += sb[0][k][c]; q2 += sb[1][k][c]; }
        const float inv = 1.f / (float)(Hn * Wn);
        float mean = s2 * inv;
        float var  = fmaxf(q2 * inv - mean * mean, 0.f);
        float sc   = 1.f / (sqrtf(var) + EPS);
        scale[b * Cn + c] = sc;
        shift[b * Cn + c] = -mean * sc;
    }
}

// ---------------- K3: norm + depthwise 3x3 + pointwise + bias -> t_pad bf16 ----------------
// grid: B*HPAD*4 (4 w-quads of 16 output cols each)
__global__ __launch_bounds__(256) void k3_dwconv(const float* __restrict__ x,
                                                 const float* __restrict__ w_sp,
                                                 const float* __restrict__ w_pw,
                                                 const float* __restrict__ bias,
                                                 const float* __restrict__ scale,
                                                 const float* __restrict__ shift,
                                                 __hip_bfloat16* __restrict__ tpad) {
    const int bq = blockIdx.x;
    const int wq = bq & 3;
    const int bh = bq >> 2;
    const int b  = bh / HPAD;
    const int hp = bh - b * HPAD;       // 0..65
    const int c  = threadIdx.x;
    __hip_bfloat16* orow = tpad + ((size_t)(b * HPAD + hp)) * WPAD * Cn + c;
    const __hip_bfloat16 z = __float2bfloat16(0.f);

    if (hp == 0 || hp == HPAD - 1) {
        int wlo = wq * 17, whi = wlo + 17 < WPAD ? wlo + 17 : WPAD;
        for (int wp = wlo; wp < whi; ++wp) orow[(size_t)wp * Cn] = z;
        return;
    }
    const int h = hp - 1;
    const float sc = scale[b * Cn + c];
    const float sh = shift[b * Cn + c];
    float w9[9];
#pragma unroll
    for (int k = 0; k < 9; ++k) w9[k] = w_sp[(b * 9 + k) * Cn + c];
    const float pw = w_pw[b * Cn + c];
    const float bv = bias[b * Cn + c];
    const float* xb = x + (size_t)b * Hn * Wn * Cn + c;

    bool rv[3];
#pragma unroll
    for (int r = 0; r < 3; ++r) { int rr = h - 1 + r; rv[r] = (rr >= 0 && rr < Hn); }

    if (wq == 0) orow[0] = z;
    if (wq == 3) orow[(size_t)(WPAD - 1) * Cn] = z;

    const int w0 = wq * 16;
    float win[3][3];
#pragma unroll
    for (int r = 0; r < 3; ++r) {
        win[r][0] = (rv[r] && w0 > 0)
                    ? (xb[((size_t)(h - 1 + r) * Wn + (w0 - 1)) * Cn] * sc + sh) : 0.f;
        win[r][1] = rv[r] ? (xb[((size_t)(h - 1 + r) * Wn + w0) * Cn] * sc + sh) : 0.f;
    }
    for (int i = 0; i < 16; ++i) {
        const int w = w0 + i;
#pragma unroll
        for (int r = 0; r < 3; ++r)
            win[r][2] = (rv[r] && (w + 1) < Wn)
                        ? (xb[((size_t)(h - 1 + r) * Wn + (w + 1)) * Cn] * sc + sh) : 0.f;
        float y = 0.f;
#pragma unroll
        for (int r = 0; r < 3; ++r)
#pragma unroll
            for (int qq = 0; qq < 3; ++qq)
                y += win[r][qq] * w9[r * 3 + qq];
        orow[(size_t)(w + 1) * Cn] = __float2bfloat16(y * pw + bv);
#pragma unroll
        for (int r = 0; r < 3; ++r) { win[r][0] = win[r][1]; win[r][1] = win[r][2]; }
    }
}

// ---------------- K4: implicit-GEMM 3x3 conv, 256x256, BK=32, 4-buffer free-run ----------------
// 512 thr = 8 waves (2m x 4n), per-wave 128x64 -> 12 ds_read_b128 / 32 MFMA per K-step.
// LDS: 2 M-rows (or 2 out-ch) packed per 128B LDS row, 8x16B slots, XOR-swizzled
// (slot' = slot ^ (ldsrow&7)) -> every 16B slot hit by exactly 2 lanes (free, m136);
// gload_lds dest stays linear, inverse swizzle applied to per-lane GLOBAL source.
// 4 buffers x 32KB = 128KB; stage 2 steps ahead; ONE barrier per step, counted vmcnt(4);
// no post-MFMA barrier -> waves free-run within a step (LDS pipe overlaps matrix pipe).
constexpr int KSTEPS = 72;              // 9 taps x (256/32)
constexpr int BUFSZ  = 32768;           // A 16KB + B 16KB

__global__ __launch_bounds__(512, 2) void k4_gemm(const __hip_bfloat16* __restrict__ tpad,
                                                  const __hip_bfloat16* __restrict__ wT,
                                                  const float* __restrict__ conv_b,
                                                  float* __restrict__ out) {
    __shared__ __align__(16) char smem[4 * BUFSZ];   // 128 KB

    const int tid  = threadIdx.x;
    const int lane = tid & 63;
    const int wv   = tid >> 6;          // 0..7
    const int wm   = wv >> 2;           // 0..1
    const int wn   = wv & 3;            // 0..3
    const int g    = lane >> 4, l15 = lane & 15;

    // XCD-chunked mapping (bijective: 8 x 16 x 4 = 512)
    const int bid = blockIdx.x;
    const int mt  = (bid & 7) * 16 + ((bid >> 3) & 15);   // 0..127
    const int nt  = bid >> 7;                             // 0..3
    const int pixbase = mt * 256;
    const int b       = mt >> 4;
    const int hbase   = (mt & 15) * 4;
    const int obase   = nt * 256;

    // ---- staging source offsets. LDS unit u = j*512 + tid (16B units, linear dest).
    // A block: u in [0,1024): ldsrow r=u>>3, phys slot p=u&7, logical l=p^(r&7),
    //          pixel = 2r + (l>>2), k-group = l&3  (involution: read uses same XOR)
    int aoff[2], boff[2];
#pragma unroll
    for (int j = 0; j < 2; ++j) {
        int u = j * 512 + tid;
        int r = u >> 3, p = u & 7;
        int l = p ^ (r & 7);
        int pix = 2 * r + (l >> 2);
        int hh  = hbase + (pix >> 6);
        int ww  = pix & 63;
        aoff[j] = ((b * HPAD + hh) * WPAD + ww) * Cn + (l & 3) * 8;
        boff[j] = (obase + 2 * r + (l >> 2)) * Cn + (l & 3) * 8;
    }

    auto stageS = [&](int s) {
        const int tap = s >> 3, ks = s & 7;
        const int kh  = tap / 3, kw = tap - 3 * kh;
        const __hip_bfloat16* aS = tpad + ((kh * WPAD + kw) * Cn + ks * 32);
        const __hip_bfloat16* bS = wT + (size_t)tap * (OUTC * Cn) + ks * 32;
        char* buf = smem + (s & 3) * BUFSZ;
        gload_lds16(aS + aoff[0], buf + (size_t)(0 * 512 + wv * 64) * 16);
        gload_lds16(aS + aoff[1], buf + (size_t)(1 * 512 + wv * 64) * 16);
        gload_lds16(bS + boff[0], buf + 16384 + (size_t)(0 * 512 + wv * 64) * 16);
        gload_lds16(bS + boff[1], buf + 16384 + (size_t)(1 * 512 + wv * 64) * 16);
    };

    f32x4 acc[8][4] = {};

    // ---- prologue: stage K-steps 0,1 (8 loads/thread) ----
    stageS(0);
    stageS(1);

#pragma unroll 1
    for (int t = 0; t < KSTEPS; ++t) {
        // counted wait: own loads for step t done (t+1's 4 stay in flight)
        if (t < KSTEPS - 1) { asm volatile("s_waitcnt vmcnt(4)" ::: "memory"); }
        else                { asm volatile("s_waitcnt vmcnt(0)" ::: "memory"); }
        __builtin_amdgcn_sched_barrier(0);
        __builtin_amdgcn_s_barrier();      // buf t now globally complete; skew < 1 step
        __builtin_amdgcn_sched_barrier(0);

        char* Ab = smem + (t & 3) * BUFSZ;
        char* Bb = Ab + 16384;

        bf16x8 bfr[4], af[8];
#pragma unroll
        for (int n = 0; n < 4; ++n) {
            int o = wn * 64 + n * 16 + l15;
            int r = o >> 1;
            bfr[n] = *(const bf16x8*)(Bb + r * 128 +
                         ((((o & 1) << 2) | g) ^ (r & 7)) * 16);
        }
#pragma unroll
        for (int m = 0; m < 8; ++m) {
            int pix = wm * 128 + m * 16 + l15;
            int r = pix >> 1;
            af[m] = *(const bf16x8*)(Ab + r * 128 +
                         ((((pix & 1) << 2) | g) ^ (r & 7)) * 16);
        }

        if (t + 2 < KSTEPS) stageS(t + 2);   // writes buf (t+2)%4 — disjoint from t%4

        __builtin_amdgcn_s_setprio(1);
#pragma unroll
        for (int m = 0; m < 8; ++m)
#pragma unroll
            for (int n = 0; n < 4; ++n)
                acc[m][n] = __builtin_amdgcn_mfma_f32_16x16x32_bf16(
                    af[m], bfr[n], acc[m][n], 0, 0, 0);
        __builtin_amdgcn_s_setprio(0);
    }

    // ---- epilogue: C frag col = l15, row = g*4+j ----
    float cb[4];
#pragma unroll
    for (int n = 0; n < 4; ++n) cb[n] = conv_b[obase + wn * 64 + n * 16 + l15];
#pragma unroll
    for (int m = 0; m < 8; ++m) {
#pragma unroll
        for (int j = 0; j < 4; ++j) {
            int r = pixbase + wm * 128 + m * 16 + g * 4 + j;
            float* orow = out + (size_t)r * OUTC + obase + wn * 64 + l15;
#pragma unroll
            for (int n = 0; n < 4; ++n)
                orow[n * 16] = acc[m][n][j] + cb[n];
        }
    }
}

// ---------------- launch ----------------
extern "C" void kernel_launch(void* const* d_in, const int* in_sizes, int n_in,
                              void* d_out, int out_size, void* d_ws, size_t ws_size,
                              hipStream_t stream) {
    const float* x      = (const float*)d_in[0];
    const float* w_sp   = (const float*)d_in[1];
    const float* w_pw   = (const float*)d_in[2];
    const float* bias   = (const float*)d_in[3];
    const float* conv_w = (const float*)d_in[4];
    const float* conv_b = (const float*)d_in[5];
    float* out = (float*)d_out;

    char* ws = (char*)d_ws;
    __hip_bfloat16* wT    = (__hip_bfloat16*)(ws);
    float*          ps    = (float*)(ws + 4718592);
    float*          pq    = (float*)(ws + 4718592 + 524288);
    float*          scale = (float*)(ws + 5767168);
    float*          shift = (float*)(ws + 5775360);
    __hip_bfloat16* tpad  = (__hip_bfloat16*)(ws + 5783552);

    k0_transpose_w<<<dim3(9, 4, 16), 256, 0, stream>>>(conv_w, wT);
    k1_stats_partial<<<Bn * Hn, 1024, 0, stream>>>(x, ps, pq);
    k2_stats_final<<<Bn, 1024, 0, stream>>>(ps, pq, scale, shift);
    k3_dwconv<<<Bn * HPAD * 4, 256, 0, stream>>>(x, w_sp, w_pw, bias, scale, shift, tpad);
    k4_gemm<<<512, 512, 0, stream>>>(tpad, wT, conv_b, out);
}